// Round 7
// baseline (853.070 us; speedup 1.0000x reference)
//
#include <hip/hip_runtime.h>
#include <cmath>

// x[32768, 256] fp32, codebook[1024, 256] fp32. Outputs fp32 flat:
// loss(1), z_q(8388608), perplexity(1), indices(32768)
#define NROWS 32768
#define DDIM  256
#define KCB   1024

constexpr float TAU = 0.35f;   // fp16-path margin for fp64 recheck (validated r4-r6)
constexpr int BSTR = 72;       // B-tile LDS stride in fp16 (144 B: aligned, dense banks)

typedef _Float16 half8 __attribute__((ext_vector_type(8)));
typedef _Float16 half4 __attribute__((ext_vector_type(4)));
typedef float floatx4 __attribute__((ext_vector_type(4)));

__global__ void init_kernel(double* __restrict__ sumsq, int* __restrict__ sumidx) {
  *sumsq = 0.0;
  *sumidx = 0;
}

// Exact codebook norms (fp64 -> fp32) and (if ws allows) fp16 codebook copy.
template<bool CVT>
__global__ __launch_bounds__(64) void prep_kernel(const float* __restrict__ cb,
                                                  float* __restrict__ cn,
                                                  _Float16* __restrict__ cbh) {
  const int k = blockIdx.x, lane = threadIdx.x;
  float4 v = *(const float4*)(cb + (size_t)k * DDIM + lane * 4);
  double s = (double)v.x * v.x + (double)v.y * v.y
           + (double)v.z * v.z + (double)v.w * v.w;
  #pragma unroll
  for (int off = 32; off; off >>= 1) s += __shfl_down(s, off);
  if (lane == 0) cn[k] = (float)s;
  if constexpr (CVT) {
    half4 h;
    h[0] = (_Float16)v.x; h[1] = (_Float16)v.y;
    h[2] = (_Float16)v.z; h[3] = (_Float16)v.w;
    *(half4*)&cbh[(size_t)k * DDIM + lane * 4] = h;
  }
}

// Block = 256 thr / 4 waves / 64 rows. A-frags in VGPRs (32 regs, converted
// once). B streamed through double-buffered LDS tiles (64 entries x 64 K fp16),
// one barrier per stage, global loads issued a full stage early. 64 stages =
// 16 col-tiles x 4 K-chunks; per wave per stage: 8 ds_read_b128 + 8 MFMA.
// dist = cn - 2*dot; best+second tracked; margin < TAU => exact fp64 re-scan.
template<bool H>
__global__ __launch_bounds__(256, 2) void fused_kernel(
    const float* __restrict__ x,
    const float* __restrict__ cb,
    const _Float16* __restrict__ cbh,
    const float* __restrict__ cn,
    float* __restrict__ zq_out,
    float* __restrict__ idx_out,
    double* __restrict__ sumsq,
    int* __restrict__ sumidx) {
  __shared__ __align__(16) _Float16 bs[2][64 * BSTR];  // 2 x 9 KB B tiles
  __shared__ float cn_lds[KCB];
  __shared__ int   bidx[64];
  __shared__ float marg[64];
  __shared__ __align__(16) float xrow[DDIM];
  __shared__ int   flist[64];
  __shared__ int   nflag;
  __shared__ float wred[4];
  __shared__ double rv[4];
  __shared__ int    ri[4];

  const int tid = threadIdx.x;
  const int lane = tid & 63;
  const int w = tid >> 6;        // wave: rows w*16 .. +15
  const int q = lane >> 4;       // quad
  const int tx = lane & 15;
  const int row0 = blockIdx.x * 64;

  // ---- A fragments: lane holds x[row0+w*16+tx][s*32 + q*8 ..+7] as fp16 ----
  half8 a[8];
  {
    const float* xp = x + (size_t)(row0 + w * 16 + tx) * DDIM + q * 8;
    #pragma unroll
    for (int s = 0; s < 8; ++s) {
      float4 v0 = *(const float4*)(xp + s * 32);
      float4 v1 = *(const float4*)(xp + s * 32 + 4);
      half8 h;
      h[0] = (_Float16)v0.x; h[1] = (_Float16)v0.y;
      h[2] = (_Float16)v0.z; h[3] = (_Float16)v0.w;
      h[4] = (_Float16)v1.x; h[5] = (_Float16)v1.y;
      h[6] = (_Float16)v1.z; h[7] = (_Float16)v1.w;
      a[s] = h;
    }
  }
  #pragma unroll
  for (int i = 0; i < 4; ++i) cn_lds[tid + 256 * i] = cn[tid + 256 * i];
  if (tid == 0) nflag = 0;

  half8 vld[2];
  // stage st: col-tile ct = st>>2 (64 entries), K-chunk kc = st&3 (64 elems).
  // slot = tid + 256*i -> entry e = slot>>3, 16B-chunk c = slot&7.
  auto load_stage = [&](int st) {
    int ct = st >> 2, kc = st & 3;
    #pragma unroll
    for (int i = 0; i < 2; ++i) {
      int slot = tid + 256 * i;
      int e = slot >> 3, c = slot & 7;
      size_t gofs = (size_t)(ct * 64 + e) * DDIM + kc * 64 + c * 8;
      if constexpr (H) {
        vld[i] = *(const half8*)&cbh[gofs];
      } else {
        const float* p = cb + gofs;
        float4 v0 = *(const float4*)p, v1 = *(const float4*)(p + 4);
        half8 h;
        h[0] = (_Float16)v0.x; h[1] = (_Float16)v0.y;
        h[2] = (_Float16)v0.z; h[3] = (_Float16)v0.w;
        h[4] = (_Float16)v1.x; h[5] = (_Float16)v1.y;
        h[6] = (_Float16)v1.z; h[7] = (_Float16)v1.w;
        vld[i] = h;
      }
    }
  };
  auto write_stage = [&](int buf) {
    #pragma unroll
    for (int i = 0; i < 2; ++i) {
      int slot = tid + 256 * i;
      int e = slot >> 3, c = slot & 7;
      *(half8*)&bs[buf][e * BSTR + c * 8] = vld[i];
    }
  };

  float minv[4], minv2[4];
  int mini[4];
  #pragma unroll
  for (int r = 0; r < 4; ++r) { minv[r] = INFINITY; minv2[r] = INFINITY; mini[r] = 0; }

  floatx4 acc[4];
  #pragma unroll
  for (int c = 0; c < 4; ++c) acc[c] = (floatx4){0.f, 0.f, 0.f, 0.f};

  load_stage(0);
  write_stage(0);
  for (int st = 0; st < 64; ++st) {
    if (st + 1 < 64) load_stage(st + 1);       // in flight during compute
    __syncthreads();                            // buf[st&1] staged & visible
    const int buf = st & 1, kc = st & 3;
    #pragma unroll
    for (int s = 0; s < 2; ++s) {
      half8 av = a[kc * 2 + s];
      #pragma unroll
      for (int ci = 0; ci < 4; ++ci) {
        half8 b = *(const half8*)&bs[buf][(ci * 16 + tx) * BSTR + (s * 4 + q) * 8];
        acc[ci] = __builtin_amdgcn_mfma_f32_16x16x32_f16(av, b, acc[ci], 0, 0, 0);
      }
    }
    if (kc == 3) {
      // epilogue for col-tile ct: C/D layout col=lane&15, row=q*4+reg
      const int ct = st >> 2;
      #pragma unroll
      for (int ci = 0; ci < 4; ++ci) {
        int col = ct * 64 + ci * 16 + tx;
        float cnv = cn_lds[col];
        #pragma unroll
        for (int r = 0; r < 4; ++r) {
          float dist = cnv - 2.f * acc[ci][r];
          if (dist < minv[r]) {
            minv2[r] = minv[r];
            minv[r] = dist; mini[r] = col;
          } else if (dist < minv2[r]) {
            minv2[r] = dist;
          }
        }
        acc[ci] = (floatx4){0.f, 0.f, 0.f, 0.f};
      }
    }
    if (st + 1 < 64) write_stage((st + 1) & 1); // other buffer: no hazard
  }

  // merge (best, idx, second) across the 16 tx-lanes of each quad
  #pragma unroll
  for (int off = 8; off; off >>= 1) {
    #pragma unroll
    for (int r = 0; r < 4; ++r) {
      float ov  = __shfl_down(minv[r],  off, 16);
      int   oi  = __shfl_down(mini[r],  off, 16);
      float ov2 = __shfl_down(minv2[r], off, 16);
      if (ov < minv[r] || (ov == minv[r] && oi < mini[r])) {
        minv2[r] = fminf(minv[r], ov2);
        minv[r] = ov; mini[r] = oi;
      } else {
        minv2[r] = fminf(minv2[r], ov);
      }
    }
  }
  if (tx == 0) {
    #pragma unroll
    for (int r = 0; r < 4; ++r) {
      int R = w * 16 + q * 4 + r;
      bidx[R] = mini[r];
      marg[R] = minv2[r] - minv[r];
    }
  }
  __syncthreads();

  if (tid < 64 && marg[tid] < TAU) {
    int p = atomicAdd(&nflag, 1);
    flist[p] = tid;
  }
  __syncthreads();

  // exact fp64 re-scan of all 1024 candidates for flagged rows (~2%)
  for (int f = 0; f < nflag; ++f) {
    int r = flist[f];
    if (tid < 64) {
      float4 v = *(const float4*)(x + (size_t)(row0 + r) * DDIM + tid * 4);
      xrow[tid * 4 + 0] = v.x; xrow[tid * 4 + 1] = v.y;
      xrow[tid * 4 + 2] = v.z; xrow[tid * 4 + 3] = v.w;
    }
    __syncthreads();
    double bestd = 1e300; int bi = 0;
    #pragma unroll
    for (int j = 0; j < 4; ++j) {
      int col = tid * 4 + j;
      const float* crow = cb + (size_t)col * DDIM;
      double s = 0.0;
      for (int d = 0; d < DDIM; d += 4) {
        float4 cv = *(const float4*)(crow + d);
        double d0 = (double)xrow[d + 0] - (double)cv.x; s = fma(d0, d0, s);
        double d1 = (double)xrow[d + 1] - (double)cv.y; s = fma(d1, d1, s);
        double d2 = (double)xrow[d + 2] - (double)cv.z; s = fma(d2, d2, s);
        double d3 = (double)xrow[d + 3] - (double)cv.w; s = fma(d3, d3, s);
      }
      if (s < bestd) { bestd = s; bi = col; }
    }
    #pragma unroll
    for (int off = 32; off; off >>= 1) {
      double ov = __shfl_down(bestd, off);
      int oi = __shfl_down(bi, off);
      if (ov < bestd || (ov == bestd && oi < bi)) { bestd = ov; bi = oi; }
    }
    if (lane == 0) { rv[w] = bestd; ri[w] = bi; }
    __syncthreads();
    if (tid == 0) {
      double bv = rv[0]; int bix = ri[0];
      for (int ww = 1; ww < 4; ++ww)
        if (rv[ww] < bv || (rv[ww] == bv && ri[ww] < bix)) { bv = rv[ww]; bix = ri[ww]; }
      bidx[r] = bix;
    }
    __syncthreads();
  }

  if (tid < 64) idx_out[row0 + tid] = (float)bidx[tid];

  // ---- gather: z_q rows (exact fp32 copies) + loss partial ----
  float lsum = 0.f;
  #pragma unroll 4
  for (int it = 0; it < 16; ++it) {
    int g = tid + 256 * it;        // 4096 float4 groups = 64 rows x 64 groups
    int r = g >> 6;
    int c4 = (g & 63) << 2;
    int k = bidx[r] & (KCB - 1);
    float4 cv = *(const float4*)(cb + (size_t)k * DDIM + c4);
    float4 xv = *(const float4*)(x + (size_t)(row0 + r) * DDIM + c4);
    float d0 = cv.x - xv.x, d1 = cv.y - xv.y, d2 = cv.z - xv.z, d3 = cv.w - xv.w;
    lsum = fmaf(d0, d0, lsum); lsum = fmaf(d1, d1, lsum);
    lsum = fmaf(d2, d2, lsum); lsum = fmaf(d3, d3, lsum);
    *(float4*)(zq_out + (size_t)(row0 + r) * DDIM + c4) = cv;
  }
  #pragma unroll
  for (int off = 32; off; off >>= 1) lsum += __shfl_down(lsum, off);
  if (lane == 0) wred[w] = lsum;
  __syncthreads();
  if (tid == 0) {
    atomicAdd(sumsq, (double)wred[0] + (double)wred[1] + (double)wred[2] + (double)wred[3]);
    int si = 0;
    #pragma unroll 8
    for (int r = 0; r < 64; ++r) si += bidx[r] & (KCB - 1);
    atomicAdd(sumidx, si);
  }
}

__global__ void finalize_kernel(const double* __restrict__ sumsq,
                                const int* __restrict__ sumidx,
                                float* __restrict__ out_loss,
                                float* __restrict__ out_perp) {
  // loss = mean(sg(zq)-x)^2 + 0.25*mean(zq-sg(x))^2 = 1.25 * MSE (fwd equal)
  double loss = 1.25 * (*sumsq) / 8388608.0;
  double e_min = (double)(*sumidx) / 32768.0;      // scalar mean of indices
  double perp = exp(-e_min * log(e_min + 1e-10));  // underflows to 0
  *out_loss = (float)loss;
  *out_perp = (float)perp;
}

extern "C" void kernel_launch(void* const* d_in, const int* in_sizes, int n_in,
                              void* d_out, int out_size, void* d_ws, size_t ws_size,
                              hipStream_t stream) {
  const float* x  = (const float*)d_in[0];   // [32768, 256] fp32
  const float* cb = (const float*)d_in[1];   // [1024, 256] fp32
  float* out = (float*)d_out;
  float* out_loss = out;                  // [0]
  float* out_zq   = out + 1;              // [1 .. 8388608]
  float* out_perp = out + 1 + 8388608;    // [8388609]
  float* out_idx  = out + 2 + 8388608;    // [8388610 ..]

  double*   sumsq  = (double*)d_ws;
  int*      sumidx = (int*)((char*)d_ws + 8);
  float*    cn     = (float*)((char*)d_ws + 16);      // 4 KB
  _Float16* cbh    = (_Float16*)((char*)d_ws + 8192); // 512 KB (optional)

  // ws_size is launch-invariant => deterministic branch (r6 ran H=true: ws OK).
  const bool useH = ws_size >= (size_t)(8192 + KCB * DDIM * 2);

  hipLaunchKernelGGL(init_kernel, dim3(1), dim3(1), 0, stream, sumsq, sumidx);
  if (useH) {
    hipLaunchKernelGGL(prep_kernel<true>, dim3(KCB), dim3(64), 0, stream, cb, cn, cbh);
    hipLaunchKernelGGL(fused_kernel<true>, dim3(NROWS / 64), dim3(256), 0, stream,
                       x, cb, cbh, cn, out_zq, out_idx, sumsq, sumidx);
  } else {
    hipLaunchKernelGGL(prep_kernel<false>, dim3(KCB), dim3(64), 0, stream, cb, cn, cbh);
    hipLaunchKernelGGL(fused_kernel<false>, dim3(NROWS / 64), dim3(256), 0, stream,
                       x, cb, cbh, cn, out_zq, out_idx, sumsq, sumidx);
  }
  hipLaunchKernelGGL(finalize_kernel, dim3(1), dim3(1), 0, stream,
                     sumsq, sumidx, out_loss, out_perp);
}

// Round 8
// 433.381 us; speedup vs baseline: 1.9684x; 1.9684x over previous
//
#include <hip/hip_runtime.h>
#include <cmath>

// x[32768, 256] fp32, codebook[1024, 256] fp32. Outputs fp32 flat:
// loss(1), z_q(8388608), perplexity(1), indices(32768)
#define NROWS 32768
#define DDIM  256
#define KCB   1024

constexpr float TAU = 0.35f;   // fp16-path margin for fp64 recheck (validated r4-r7)
constexpr int BSTR = 264;      // B-tile LDS row stride in fp16 (528 B == 4 dw mod 32:
                               // exactly 8 dwords/bank for frag reads AND stage writes)

typedef _Float16 half8 __attribute__((ext_vector_type(8)));
typedef _Float16 half4 __attribute__((ext_vector_type(4)));
typedef float floatx4 __attribute__((ext_vector_type(4)));

__global__ void init_kernel(double* __restrict__ sumsq, int* __restrict__ sumidx) {
  *sumsq = 0.0;
  *sumidx = 0;
}

// Exact codebook norms (fp64 -> fp32) and (if ws allows) fp16 codebook copy.
template<bool CVT>
__global__ __launch_bounds__(64) void prep_kernel(const float* __restrict__ cb,
                                                  float* __restrict__ cn,
                                                  _Float16* __restrict__ cbh) {
  const int k = blockIdx.x, lane = threadIdx.x;
  float4 v = *(const float4*)(cb + (size_t)k * DDIM + lane * 4);
  double s = (double)v.x * v.x + (double)v.y * v.y
           + (double)v.z * v.z + (double)v.w * v.w;
  #pragma unroll
  for (int off = 32; off; off >>= 1) s += __shfl_down(s, off);
  if (lane == 0) cn[k] = (float)s;
  if constexpr (CVT) {
    half4 h;
    h[0] = (_Float16)v.x; h[1] = (_Float16)v.y;
    h[2] = (_Float16)v.z; h[3] = (_Float16)v.w;
    *(half4*)&cbh[(size_t)k * DDIM + lane * 4] = h;
  }
}

// Block = 256 thr / 4 waves / 64 rows. A-frags in VGPRs (converted once).
// Stage = one col-tile: 64 entries x K=256 fp16 (32 KB), double-buffered.
// Pipeline per stage: write(st) -> barrier -> issue loads(st+1) -> compute(st)
// (32 MFMA/wave). Prefetch latency overlaps compute and never meets a barrier
// drain. 16 barriers total. dist = cn - 2*dot; best+second tracked; rows with
// margin < TAU get an exact in-block fp64 re-scan (indices == fp64 argmin).
template<bool H>
__global__ __launch_bounds__(256, 2) void fused_kernel(
    const float* __restrict__ x,
    const float* __restrict__ cb,
    const _Float16* __restrict__ cbh,
    const float* __restrict__ cn,
    float* __restrict__ zq_out,
    float* __restrict__ idx_out,
    double* __restrict__ sumsq,
    int* __restrict__ sumidx) {
  __shared__ __align__(16) _Float16 bs[2][64 * BSTR];  // 2 x 33 KB B tiles
  __shared__ float cn_lds[KCB];
  __shared__ int   bidx[64];
  __shared__ float marg[64];
  __shared__ __align__(16) float xrow[DDIM];
  __shared__ int   flist[64];
  __shared__ int   nflag;
  __shared__ float wred[4];
  __shared__ double rv[4];
  __shared__ int    ri[4];

  const int tid = threadIdx.x;
  const int lane = tid & 63;
  const int w = tid >> 6;        // wave: rows w*16 .. +15
  const int q = lane >> 4;       // quad
  const int tx = lane & 15;
  const int row0 = blockIdx.x * 64;

  // ---- A fragments: lane holds x[row0+w*16+tx][s*32 + q*8 ..+7] as fp16 ----
  half8 a[8];
  {
    const float* xp = x + (size_t)(row0 + w * 16 + tx) * DDIM + q * 8;
    #pragma unroll
    for (int s = 0; s < 8; ++s) {
      float4 v0 = *(const float4*)(xp + s * 32);
      float4 v1 = *(const float4*)(xp + s * 32 + 4);
      half8 h;
      h[0] = (_Float16)v0.x; h[1] = (_Float16)v0.y;
      h[2] = (_Float16)v0.z; h[3] = (_Float16)v0.w;
      h[4] = (_Float16)v1.x; h[5] = (_Float16)v1.y;
      h[6] = (_Float16)v1.z; h[7] = (_Float16)v1.w;
      a[s] = h;
    }
  }
  #pragma unroll
  for (int i = 0; i < 4; ++i) cn_lds[tid + 256 * i] = cn[tid + 256 * i];
  if (tid == 0) nflag = 0;

  // stage ct: 2048 16B-slots; slot = tid + 256*i -> entry e=slot>>5, chunk c=slot&31
  half8 vld[8];
  auto load_stage = [&](int ct) {
    #pragma unroll
    for (int i = 0; i < 8; ++i) {
      int slot = tid + 256 * i;
      if constexpr (H) {
        vld[i] = *(const half8*)&cbh[(size_t)ct * 16384 + slot * 8];
      } else {
        const float* p = cb + (size_t)ct * 16384 + slot * 8;
        float4 v0 = *(const float4*)p, v1 = *(const float4*)(p + 4);
        half8 h;
        h[0] = (_Float16)v0.x; h[1] = (_Float16)v0.y;
        h[2] = (_Float16)v0.z; h[3] = (_Float16)v0.w;
        h[4] = (_Float16)v1.x; h[5] = (_Float16)v1.y;
        h[6] = (_Float16)v1.z; h[7] = (_Float16)v1.w;
        vld[i] = h;
      }
    }
  };
  auto write_stage = [&](int buf) {
    #pragma unroll
    for (int i = 0; i < 8; ++i) {
      int slot = tid + 256 * i;
      int e = slot >> 5, c = slot & 31;
      *(half8*)&bs[buf][e * BSTR + c * 8] = vld[i];
    }
  };

  float minv[4], minv2[4];
  int mini[4];
  #pragma unroll
  for (int r = 0; r < 4; ++r) { minv[r] = INFINITY; minv2[r] = INFINITY; mini[r] = 0; }

  load_stage(0);
  for (int st = 0; st < 16; ++st) {
    const int buf = st & 1;
    write_stage(buf);            // consumes loads issued last iter (vmcnt wait here)
    __syncthreads();             // tile visible; prev tile's readers done
    if (st + 1 < 16) load_stage(st + 1);   // in flight across compute(st)

    floatx4 acc[4];
    #pragma unroll
    for (int c = 0; c < 4; ++c) acc[c] = (floatx4){0.f, 0.f, 0.f, 0.f};

    #pragma unroll
    for (int s = 0; s < 8; ++s) {
      half8 av = a[s];
      #pragma unroll
      for (int ci = 0; ci < 4; ++ci) {
        half8 b = *(const half8*)&bs[buf][(ci * 16 + tx) * BSTR + (s * 4 + q) * 8];
        acc[ci] = __builtin_amdgcn_mfma_f32_16x16x32_f16(av, b, acc[ci], 0, 0, 0);
      }
    }

    // epilogue: C/D layout col=lane&15, row=q*4+reg
    #pragma unroll
    for (int ci = 0; ci < 4; ++ci) {
      int col = st * 64 + ci * 16 + tx;
      float cnv = cn_lds[col];
      #pragma unroll
      for (int r = 0; r < 4; ++r) {
        float dist = cnv - 2.f * acc[ci][r];
        if (dist < minv[r]) {
          minv2[r] = minv[r];
          minv[r] = dist; mini[r] = col;
        } else if (dist < minv2[r]) {
          minv2[r] = dist;
        }
      }
    }
  }

  // merge (best, idx, second) across the 16 tx-lanes of each quad
  #pragma unroll
  for (int off = 8; off; off >>= 1) {
    #pragma unroll
    for (int r = 0; r < 4; ++r) {
      float ov  = __shfl_down(minv[r],  off, 16);
      int   oi  = __shfl_down(mini[r],  off, 16);
      float ov2 = __shfl_down(minv2[r], off, 16);
      if (ov < minv[r] || (ov == minv[r] && oi < mini[r])) {
        minv2[r] = fminf(minv[r], ov2);
        minv[r] = ov; mini[r] = oi;
      } else {
        minv2[r] = fminf(minv2[r], ov);
      }
    }
  }
  if (tx == 0) {
    #pragma unroll
    for (int r = 0; r < 4; ++r) {
      int R = w * 16 + q * 4 + r;
      bidx[R] = mini[r];
      marg[R] = minv2[r] - minv[r];
    }
  }
  __syncthreads();

  if (tid < 64 && marg[tid] < TAU) {
    int p = atomicAdd(&nflag, 1);
    flist[p] = tid;
  }
  __syncthreads();

  // exact fp64 re-scan of all 1024 candidates for flagged rows (~2%)
  for (int f = 0; f < nflag; ++f) {
    int r = flist[f];
    if (tid < 64) {
      float4 v = *(const float4*)(x + (size_t)(row0 + r) * DDIM + tid * 4);
      xrow[tid * 4 + 0] = v.x; xrow[tid * 4 + 1] = v.y;
      xrow[tid * 4 + 2] = v.z; xrow[tid * 4 + 3] = v.w;
    }
    __syncthreads();
    double bestd = 1e300; int bi = 0;
    #pragma unroll
    for (int j = 0; j < 4; ++j) {
      int col = tid * 4 + j;
      const float* crow = cb + (size_t)col * DDIM;
      double s = 0.0;
      for (int d = 0; d < DDIM; d += 4) {
        float4 cv = *(const float4*)(crow + d);
        double d0 = (double)xrow[d + 0] - (double)cv.x; s = fma(d0, d0, s);
        double d1 = (double)xrow[d + 1] - (double)cv.y; s = fma(d1, d1, s);
        double d2 = (double)xrow[d + 2] - (double)cv.z; s = fma(d2, d2, s);
        double d3 = (double)xrow[d + 3] - (double)cv.w; s = fma(d3, d3, s);
      }
      if (s < bestd) { bestd = s; bi = col; }
    }
    #pragma unroll
    for (int off = 32; off; off >>= 1) {
      double ov = __shfl_down(bestd, off);
      int oi = __shfl_down(bi, off);
      if (ov < bestd || (ov == bestd && oi < bi)) { bestd = ov; bi = oi; }
    }
    if (lane == 0) { rv[w] = bestd; ri[w] = bi; }
    __syncthreads();
    if (tid == 0) {
      double bv = rv[0]; int bix = ri[0];
      for (int ww = 1; ww < 4; ++ww)
        if (rv[ww] < bv || (rv[ww] == bv && ri[ww] < bix)) { bv = rv[ww]; bix = ri[ww]; }
      bidx[r] = bix;
    }
    __syncthreads();
  }

  if (tid < 64) idx_out[row0 + tid] = (float)bidx[tid];

  // ---- gather: z_q rows (exact fp32 copies) + loss partial ----
  float lsum = 0.f;
  #pragma unroll 4
  for (int it = 0; it < 16; ++it) {
    int g = tid + 256 * it;        // 4096 float4 groups = 64 rows x 64 groups
    int r = g >> 6;
    int c4 = (g & 63) << 2;
    int k = bidx[r] & (KCB - 1);
    float4 cv = *(const float4*)(cb + (size_t)k * DDIM + c4);
    float4 xv = *(const float4*)(x + (size_t)(row0 + r) * DDIM + c4);
    float d0 = cv.x - xv.x, d1 = cv.y - xv.y, d2 = cv.z - xv.z, d3 = cv.w - xv.w;
    lsum = fmaf(d0, d0, lsum); lsum = fmaf(d1, d1, lsum);
    lsum = fmaf(d2, d2, lsum); lsum = fmaf(d3, d3, lsum);
    *(float4*)(zq_out + (size_t)(row0 + r) * DDIM + c4) = cv;
  }
  #pragma unroll
  for (int off = 32; off; off >>= 1) lsum += __shfl_down(lsum, off);
  if (lane == 0) wred[w] = lsum;
  __syncthreads();
  if (tid == 0) {
    atomicAdd(sumsq, (double)wred[0] + (double)wred[1] + (double)wred[2] + (double)wred[3]);
    int si = 0;
    #pragma unroll 8
    for (int r = 0; r < 64; ++r) si += bidx[r] & (KCB - 1);
    atomicAdd(sumidx, si);
  }
}

__global__ void finalize_kernel(const double* __restrict__ sumsq,
                                const int* __restrict__ sumidx,
                                float* __restrict__ out_loss,
                                float* __restrict__ out_perp) {
  // loss = mean(sg(zq)-x)^2 + 0.25*mean(zq-sg(x))^2 = 1.25 * MSE (fwd equal)
  double loss = 1.25 * (*sumsq) / 8388608.0;
  double e_min = (double)(*sumidx) / 32768.0;      // scalar mean of indices
  double perp = exp(-e_min * log(e_min + 1e-10));  // underflows to 0
  *out_loss = (float)loss;
  *out_perp = (float)perp;
}

extern "C" void kernel_launch(void* const* d_in, const int* in_sizes, int n_in,
                              void* d_out, int out_size, void* d_ws, size_t ws_size,
                              hipStream_t stream) {
  const float* x  = (const float*)d_in[0];   // [32768, 256] fp32
  const float* cb = (const float*)d_in[1];   // [1024, 256] fp32
  float* out = (float*)d_out;
  float* out_loss = out;                  // [0]
  float* out_zq   = out + 1;              // [1 .. 8388608]
  float* out_perp = out + 1 + 8388608;    // [8388609]
  float* out_idx  = out + 2 + 8388608;    // [8388610 ..]

  double*   sumsq  = (double*)d_ws;
  int*      sumidx = (int*)((char*)d_ws + 8);
  float*    cn     = (float*)((char*)d_ws + 16);      // 4 KB
  _Float16* cbh    = (_Float16*)((char*)d_ws + 8192); // 512 KB (optional)

  // ws_size is launch-invariant => deterministic branch (r6/r7 ran H=true).
  const bool useH = ws_size >= (size_t)(8192 + KCB * DDIM * 2);

  hipLaunchKernelGGL(init_kernel, dim3(1), dim3(1), 0, stream, sumsq, sumidx);
  if (useH) {
    hipLaunchKernelGGL(prep_kernel<true>, dim3(KCB), dim3(64), 0, stream, cb, cn, cbh);
    hipLaunchKernelGGL(fused_kernel<true>, dim3(NROWS / 64), dim3(256), 0, stream,
                       x, cb, cbh, cn, out_zq, out_idx, sumsq, sumidx);
  } else {
    hipLaunchKernelGGL(prep_kernel<false>, dim3(KCB), dim3(64), 0, stream, cb, cn, cbh);
    hipLaunchKernelGGL(fused_kernel<false>, dim3(NROWS / 64), dim3(256), 0, stream,
                       x, cb, cbh, cn, out_zq, out_idx, sumsq, sumidx);
  }
  hipLaunchKernelGGL(finalize_kernel, dim3(1), dim3(1), 0, stream,
                     sumsq, sumidx, out_loss, out_perp);
}